// Round 1
// baseline (1476.892 us; speedup 1.0000x reference)
//
#include <hip/hip_runtime.h>
#include <hip/hip_bf16.h>

typedef unsigned short u16;
typedef __attribute__((ext_vector_type(8))) __bf16 bf16x8;
typedef __attribute__((ext_vector_type(4))) float floatx4;

__device__ __forceinline__ u16 f2bf(float f){
  union { float f; unsigned u; } v; v.f = f;
  unsigned u = v.u;
  return (u16)((u + 0x7fffu + ((u >> 16) & 1u)) >> 16);
}

__device__ __forceinline__ floatx4 mfma16(bf16x8 a, bf16x8 b, floatx4 c){
  return __builtin_amdgcn_mfma_f32_16x16x32_bf16(a, b, c, 0, 0, 0);
}

// ------------------------------ elementwise ------------------------------
__global__ __launch_bounds__(256) void cast_k(const float* __restrict__ src, u16* __restrict__ dst, int n4){
  int i = blockIdx.x*256 + threadIdx.x;
  if (i >= n4) return;
  float4 v = ((const float4*)src)[i];
  ushort4 o; o.x=f2bf(v.x); o.y=f2bf(v.y); o.z=f2bf(v.z); o.w=f2bf(v.w);
  ((ushort4*)dst)[i] = o;
}

__global__ __launch_bounds__(256) void rmsnorm_k(const float* __restrict__ x, const float* __restrict__ w,
                                                 u16* __restrict__ ob, float* __restrict__ of){
  const int row = blockIdx.x, t = threadIdx.x;
  float4 v = ((const float4*)(x + (size_t)row*1024))[t];
  float ss = v.x*v.x + v.y*v.y + v.z*v.z + v.w*v.w;
  #pragma unroll
  for (int o=32;o>0;o>>=1) ss += __shfl_down(ss, o);
  __shared__ float red[4];
  if ((t&63)==0) red[t>>6]=ss;
  __syncthreads();
  float sc = rsqrtf((red[0]+red[1]+red[2]+red[3])*(1.0f/1024.0f) + 1e-5f);
  float4 wv = ((const float4*)w)[t];
  float o0=v.x*sc*wv.x, o1=v.y*sc*wv.y, o2=v.z*sc*wv.z, o3=v.w*sc*wv.w;
  ushort4 q; q.x=f2bf(o0); q.y=f2bf(o1); q.z=f2bf(o2); q.w=f2bf(o3);
  ((ushort4*)(ob + (size_t)row*1024))[t] = q;
  if (of){ float4 f4; f4.x=o0; f4.y=o1; f4.z=o2; f4.w=o3; ((float4*)(of + (size_t)row*1024))[t] = f4; }
}

__global__ __launch_bounds__(256) void rope_k(const float* __restrict__ src, u16* __restrict__ dst,
                                              const float* __restrict__ cosb, const float* __restrict__ sinb,
                                              int NH, int n){
  int idx = blockIdx.x*256 + threadIdx.x;
  if (idx >= n) return;
  int i = idx & 31;
  int rest = idx >> 5;
  int h = rest % NH;
  int bs = rest / NH;
  int s = bs & 1023;
  size_t p = (((size_t)bs*NH) + h)*64 + 2*i;
  float a = src[p], b = src[p+1];
  float c = cosb[s*32+i], sn = sinb[s*32+i];
  dst[p]   = f2bf(a*c - b*sn);
  dst[p+1] = f2bf(a*sn + b*c);
}

__global__ __launch_bounds__(256) void final_add(const float* __restrict__ h, const float* __restrict__ s0,
                                                 const float* __restrict__ s1, float* __restrict__ out, int n4){
  int i = blockIdx.x*256 + threadIdx.x;
  if (i >= n4) return;
  float4 a = ((const float4*)h)[i], b = ((const float4*)s0)[i], c = ((const float4*)s1)[i];
  float4 o; o.x=a.x+b.x+c.x; o.y=a.y+b.y+c.y; o.z=a.z+b.z+c.z; o.w=a.w+b.w+c.w;
  ((float4*)out)[i] = o;
}

// ------------------------------ generic 64x64 MFMA GEMM ------------------------------
// C[M,N] = A[M,K](bf16,row-major) @ B[K,N](bf16,row-major)
// EPI: 0 = store fp32, 1 = store bf16, 2 = store fp32 + resid
#define LDP 40   // padded LDS row stride (shorts); 80B rows keep 16B alignment, <=2-way banks

template<int EPI>
__global__ __launch_bounds__(256) void gemm64(const u16* __restrict__ A, const u16* __restrict__ B,
                                              int M, int N, int K,
                                              float* __restrict__ Cf, u16* __restrict__ Cb,
                                              const float* __restrict__ resid){
  __shared__ u16 As[64*LDP];
  __shared__ u16 Bs[64*LDP];
  const int t = threadIdx.x;
  const int nbase = blockIdx.x*64, mbase = blockIdx.y*64;
  const int wv = t>>6, lane = t&63, lrow = lane&15, quad = lane>>4;
  const int ar = t>>2, ac = (t&3)*8;
  const int br = t>>3, bc = (t&7)*8;
  floatx4 acc[4];
  #pragma unroll
  for (int i=0;i<4;++i) acc[i] = floatx4{0.f,0.f,0.f,0.f};
  for (int k0=0;k0<K;k0+=32){
    __syncthreads();
    { uint4 v = *(const uint4*)(A + (size_t)(mbase+ar)*K + k0 + ac);
      *(uint4*)(&As[ar*LDP+ac]) = v; }
    { uint4 v = *(const uint4*)(B + (size_t)(k0+br)*N + nbase + bc);
      const u16* s=(const u16*)&v;
      #pragma unroll
      for (int j=0;j<8;++j) Bs[(bc+j)*LDP + br] = s[j]; }
    __syncthreads();
    bf16x8 a = *(const bf16x8*)(&As[(wv*16+lrow)*LDP + quad*8]);
    #pragma unroll
    for (int nt=0;nt<4;++nt){
      bf16x8 b = *(const bf16x8*)(&Bs[(nt*16+lrow)*LDP + quad*8]);
      acc[nt] = mfma16(a,b,acc[nt]);
    }
  }
  #pragma unroll
  for (int nt=0;nt<4;++nt)
  #pragma unroll
  for (int i=0;i<4;++i){
    int row = mbase + wv*16 + quad*4 + i;
    int col = nbase + nt*16 + lrow;
    float val = acc[nt][i];
    if (EPI==2) val += resid[(size_t)row*N + col];
    if (EPI==1) Cb[(size_t)row*N + col] = f2bf(val);
    else        Cf[(size_t)row*N + col] = val;
  }
}

// ------------------------------ flash attention (bf16 MFMA) ------------------------------
#define ATS 72
__global__ __launch_bounds__(256) void attn_k(const u16* __restrict__ qb, const u16* __restrict__ kb,
                                              const u16* __restrict__ vb, u16* __restrict__ ob){
  const int qt = blockIdx.x, h = blockIdx.y, b = blockIdx.z;
  const int kvh = h >> 2;
  __shared__ u16 Qs[64*ATS];
  __shared__ u16 Ks[64*ATS];
  __shared__ u16 Vt[64*ATS];
  __shared__ u16 Ps[4*16*ATS];
  const int t = threadIdx.x;
  const int wv = t>>6, lane = t&63, lrow = lane&15, quad = lane>>4;
  const int q0 = qt*64;
  const float NEG_INF = -__builtin_inff();
  { // stage Q tile (64x64) once
    const int r = t>>2, c0 = (t&3)*16;
    const u16* src = qb + ((((size_t)(b*1024 + q0 + r))*16) + h)*64 + c0;
    *(uint4*)(&Qs[r*ATS + c0])     = *(const uint4*)(src);
    *(uint4*)(&Qs[r*ATS + c0 + 8]) = *(const uint4*)(src + 8);
  }
  floatx4 out[4];
  #pragma unroll
  for (int i=0;i<4;++i) out[i] = floatx4{0.f,0.f,0.f,0.f};
  float m_i[4], l_i[4];
  #pragma unroll
  for (int i=0;i<4;++i){ m_i[i] = NEG_INF; l_i[i] = 0.f; }

  for (int kt=0; kt<=qt; ++kt){
    const int k0 = kt*64;
    __syncthreads();
    { // stage K tile rows (direct: B^T layout for scores)
      const int r = t>>2, c0 = (t&3)*16;
      const u16* src = kb + ((((size_t)(b*1024 + k0 + r))*4) + kvh)*64 + c0;
      *(uint4*)(&Ks[r*ATS + c0])     = *(const uint4*)(src);
      *(uint4*)(&Ks[r*ATS + c0 + 8]) = *(const uint4*)(src + 8);
    }
    { // stage V transposed (Vt[d][k])
      const int r = t>>3, c0 = (t&7)*8;
      #pragma unroll
      for (int half=0; half<2; ++half){
        int rr = r + half*32;
        uint4 v = *(const uint4*)(vb + ((((size_t)(b*1024 + k0 + rr))*4) + kvh)*64 + c0);
        const u16* s = (const u16*)&v;
        #pragma unroll
        for (int j=0;j<8;++j) Vt[(c0+j)*ATS + rr] = s[j];
      }
    }
    __syncthreads();
    // scores S = Q K^T
    floatx4 sc[4];
    #pragma unroll
    for (int i=0;i<4;++i) sc[i] = floatx4{0.f,0.f,0.f,0.f};
    #pragma unroll
    for (int ks=0; ks<2; ++ks){
      bf16x8 af = *(const bf16x8*)(&Qs[(wv*16+lrow)*ATS + ks*32 + quad*8]);
      #pragma unroll
      for (int nt=0;nt<4;++nt){
        bf16x8 bf = *(const bf16x8*)(&Ks[(nt*16+lrow)*ATS + ks*32 + quad*8]);
        sc[nt] = mfma16(af, bf, sc[nt]);
      }
    }
    const bool diag = (kt==qt);
    float rmax[4] = {NEG_INF,NEG_INF,NEG_INF,NEG_INF};
    #pragma unroll
    for (int nt=0;nt<4;++nt)
    #pragma unroll
    for (int i=0;i<4;++i){
      float s = sc[nt][i]*0.125f;
      if (diag && (nt*16+lrow > wv*16 + quad*4 + i)) s = NEG_INF;
      sc[nt][i] = s;
      rmax[i] = fmaxf(rmax[i], s);
    }
    #pragma unroll
    for (int o=1;o<16;o<<=1)
      #pragma unroll
      for (int i=0;i<4;++i) rmax[i] = fmaxf(rmax[i], __shfl_xor(rmax[i], o));
    float al[4], psum[4] = {0.f,0.f,0.f,0.f};
    #pragma unroll
    for (int i=0;i<4;++i){
      float mn = fmaxf(m_i[i], rmax[i]);
      al[i] = expf(m_i[i]-mn);
      m_i[i] = mn;
    }
    #pragma unroll
    for (int nt=0;nt<4;++nt)
    #pragma unroll
    for (int i=0;i<4;++i){
      float p = expf(sc[nt][i]-m_i[i]);
      sc[nt][i] = p;
      psum[i] += p;
    }
    #pragma unroll
    for (int o=1;o<16;o<<=1)
      #pragma unroll
      for (int i=0;i<4;++i) psum[i] += __shfl_xor(psum[i], o);
    #pragma unroll
    for (int i=0;i<4;++i) l_i[i] = l_i[i]*al[i] + psum[i];
    #pragma unroll
    for (int nt=0;nt<4;++nt)
      #pragma unroll
      for (int i=0;i<4;++i) out[nt][i] *= al[i];
    // P (C-layout) -> LDS -> A-operand layout
    u16* Pw = &Ps[wv*16*ATS];
    #pragma unroll
    for (int nt=0;nt<4;++nt)
    #pragma unroll
    for (int i=0;i<4;++i)
      Pw[(quad*4+i)*ATS + nt*16 + lrow] = f2bf(sc[nt][i]);
    __syncthreads();
    #pragma unroll
    for (int ks=0; ks<2; ++ks){
      bf16x8 af = *(const bf16x8*)(&Pw[lrow*ATS + ks*32 + quad*8]);
      #pragma unroll
      for (int nt=0;nt<4;++nt){
        bf16x8 bf = *(const bf16x8*)(&Vt[(nt*16+lrow)*ATS + ks*32 + quad*8]);
        out[nt] = mfma16(af, bf, out[nt]);
      }
    }
  }
  #pragma unroll
  for (int nt=0;nt<4;++nt)
  #pragma unroll
  for (int i=0;i<4;++i){
    int row = q0 + wv*16 + quad*4 + i;
    float o = out[nt][i] / l_i[i];
    ob[((size_t)(b*1024 + row))*1024 + h*64 + nt*16 + lrow] = f2bf(o);
  }
}

// ------------------------------ MoE routing ------------------------------
__global__ void init_k(int* counts){ if (threadIdx.x < 8) counts[threadIdx.x] = 0; }

__global__ __launch_bounds__(256) void gate_top2(const float* __restrict__ hn, const float* __restrict__ gw,
                                                 int2* __restrict__ tidx, float2* __restrict__ tw,
                                                 int* __restrict__ counts){
  const int token = blockIdx.x*4 + (threadIdx.x>>6);
  const int lane = threadIdx.x & 63;
  const float* xr = hn + (size_t)token*1024;
  float acc[8] = {0,0,0,0,0,0,0,0};
  for (int it=0; it<16; ++it){
    int d = lane + it*64;
    float xv = xr[d];
    const float4* g4 = (const float4*)(gw + d*8);
    float4 g0 = g4[0], g1 = g4[1];
    acc[0] += xv*g0.x; acc[1] += xv*g0.y; acc[2] += xv*g0.z; acc[3] += xv*g0.w;
    acc[4] += xv*g1.x; acc[5] += xv*g1.y; acc[6] += xv*g1.z; acc[7] += xv*g1.w;
  }
  #pragma unroll
  for (int o=1;o<64;o<<=1)
    #pragma unroll
    for (int e=0;e<8;++e) acc[e] += __shfl_xor(acc[e], o);
  if (lane==0){
    int i0=0; float v0=acc[0];
    #pragma unroll
    for (int e=1;e<8;++e) if (acc[e] > v0){ v0=acc[e]; i0=e; }
    int i1=-1; float v1=-__builtin_inff();
    #pragma unroll
    for (int e=0;e<8;++e) if (e!=i0 && acc[e] > v1){ v1=acc[e]; i1=e; }
    float e2 = expf(v1 - v0);
    float w0 = 1.0f/(1.0f+e2);
    float w1 = e2/(1.0f+e2);
    int2 ii; ii.x=i0; ii.y=i1; tidx[token]=ii;
    float2 ww; ww.x=w0; ww.y=w1; tw[token]=ww;
    atomicAdd(&counts[i0],1);
    atomicAdd(&counts[i1],1);
  }
}

__global__ void offsets_k(const int* __restrict__ counts, int* __restrict__ poff, int* __restrict__ pcur){
  if (threadIdx.x==0){
    int run=0;
    for (int e=0;e<8;++e){ poff[e]=run; pcur[e]=run; run+=counts[e]; }
  }
}

__global__ __launch_bounds__(256) void scatter_k(const int2* __restrict__ tidx, const float2* __restrict__ tw,
                                                 int* __restrict__ pcur, int* __restrict__ meta,
                                                 float* __restrict__ pw){
  int t = blockIdx.x*256 + threadIdx.x;
  if (t >= 4096) return;
  int2 ii = tidx[t]; float2 ww = tw[t];
  int p0 = atomicAdd(&pcur[ii.x],1); meta[p0] = t*2;   pw[p0] = ww.x;
  int p1 = atomicAdd(&pcur[ii.y],1); meta[p1] = t*2+1; pw[p1] = ww.y;
}

// ------------------------------ MoE GEMMs ------------------------------
__global__ __launch_bounds__(256) void moe_up(const u16* __restrict__ hn_bf,
                                              const u16* __restrict__ w1, const u16* __restrict__ w3,
                                              const int* __restrict__ meta, const int* __restrict__ poff,
                                              const int* __restrict__ pcnt, u16* __restrict__ g_pool){
  const int e = blockIdx.z;
  const int cnt = pcnt[e];
  const int mloc0 = blockIdx.y*64;
  if (mloc0 >= cnt) return;
  const int base = poff[e];
  __shared__ u16 As[64*LDP], B1s[64*LDP], B3s[64*LDP];
  __shared__ int toks[64];
  const int t = threadIdx.x;
  if (t < 64){
    int ml = mloc0 + t;
    toks[t] = (ml < cnt) ? (meta[base+ml] >> 1) : -1;
  }
  const u16* B1 = w1 + (size_t)e*1024*2816;
  const u16* B3 = w3 + (size_t)e*1024*2816;
  const int nbase = blockIdx.x*64;
  const int wv = t>>6, lane = t&63, lrow = lane&15, quad = lane>>4;
  const int ar = t>>2, ac = (t&3)*8;
  const int br = t>>3, bc = (t&7)*8;
  floatx4 a1[4], a3[4];
  #pragma unroll
  for (int i=0;i<4;++i){ a1[i]=floatx4{0.f,0.f,0.f,0.f}; a3[i]=floatx4{0.f,0.f,0.f,0.f}; }
  for (int k0=0;k0<1024;k0+=32){
    __syncthreads();
    { int tok = toks[ar];
      uint4 v = {0,0,0,0};
      if (tok >= 0) v = *(const uint4*)(hn_bf + (size_t)tok*1024 + k0 + ac);
      *(uint4*)(&As[ar*LDP+ac]) = v; }
    { uint4 v = *(const uint4*)(B1 + (size_t)(k0+br)*2816 + nbase + bc);
      const u16* s=(const u16*)&v;
      #pragma unroll
      for (int j=0;j<8;++j) B1s[(bc+j)*LDP + br] = s[j]; }
    { uint4 v = *(const uint4*)(B3 + (size_t)(k0+br)*2816 + nbase + bc);
      const u16* s=(const u16*)&v;
      #pragma unroll
      for (int j=0;j<8;++j) B3s[(bc+j)*LDP + br] = s[j]; }
    __syncthreads();
    bf16x8 a = *(const bf16x8*)(&As[(wv*16+lrow)*LDP + quad*8]);
    #pragma unroll
    for (int nt=0;nt<4;++nt){
      bf16x8 b1 = *(const bf16x8*)(&B1s[(nt*16+lrow)*LDP + quad*8]);
      a1[nt] = mfma16(a,b1,a1[nt]);
      bf16x8 b3 = *(const bf16x8*)(&B3s[(nt*16+lrow)*LDP + quad*8]);
      a3[nt] = mfma16(a,b3,a3[nt]);
    }
  }
  #pragma unroll
  for (int nt=0;nt<4;++nt)
  #pragma unroll
  for (int i=0;i<4;++i){
    int ml = mloc0 + wv*16 + quad*4 + i;
    if (ml < cnt){
      float x1 = a1[nt][i], x3 = a3[nt][i];
      float g = (x1 / (1.0f + expf(-x1))) * x3;
      g_pool[(size_t)(base+ml)*2816 + nbase + nt*16 + lrow] = f2bf(g);
    }
  }
}

__global__ __launch_bounds__(256) void moe_down(const u16* __restrict__ g_pool, const u16* __restrict__ w2,
                                                const int* __restrict__ meta, const float* __restrict__ pw,
                                                const int* __restrict__ poff, const int* __restrict__ pcnt,
                                                float* __restrict__ out_slot){
  const int e = blockIdx.z;
  const int cnt = pcnt[e];
  const int mloc0 = blockIdx.y*64;
  if (mloc0 >= cnt) return;
  const int base = poff[e];
  const u16* B = w2 + (size_t)e*2816*1024;
  __shared__ u16 As[64*LDP], Bs[64*LDP];
  const int t = threadIdx.x;
  const int nbase = blockIdx.x*64;
  const int wv = t>>6, lane = t&63, lrow = lane&15, quad = lane>>4;
  const int ar = t>>2, ac = (t&3)*8;
  const int br = t>>3, bc = (t&7)*8;
  floatx4 acc[4];
  #pragma unroll
  for (int i=0;i<4;++i) acc[i]=floatx4{0.f,0.f,0.f,0.f};
  for (int k0=0;k0<2816;k0+=32){
    __syncthreads();
    { int ml = mloc0 + ar;
      uint4 v = {0,0,0,0};
      if (ml < cnt) v = *(const uint4*)(g_pool + (size_t)(base+ml)*2816 + k0 + ac);
      *(uint4*)(&As[ar*LDP+ac]) = v; }
    { uint4 v = *(const uint4*)(B + (size_t)(k0+br)*1024 + nbase + bc);
      const u16* s=(const u16*)&v;
      #pragma unroll
      for (int j=0;j<8;++j) Bs[(bc+j)*LDP + br] = s[j]; }
    __syncthreads();
    bf16x8 a = *(const bf16x8*)(&As[(wv*16+lrow)*LDP + quad*8]);
    #pragma unroll
    for (int nt=0;nt<4;++nt){
      bf16x8 b = *(const bf16x8*)(&Bs[(nt*16+lrow)*LDP + quad*8]);
      acc[nt] = mfma16(a,b,acc[nt]);
    }
  }
  #pragma unroll
  for (int nt=0;nt<4;++nt)
  #pragma unroll
  for (int i=0;i<4;++i){
    int ml = mloc0 + wv*16 + quad*4 + i;
    if (ml < cnt){
      int mm = meta[base+ml];
      int token = mm >> 1, slot = mm & 1;
      float wgt = pw[base+ml];
      out_slot[(size_t)slot*4194304 + (size_t)token*1024 + nbase + nt*16 + lrow] = wgt * acc[nt][i];
    }
  }
}

// ------------------------------ launcher ------------------------------
extern "C" void kernel_launch(void* const* d_in, const int* in_sizes, int n_in,
                              void* d_out, int out_size, void* d_ws, size_t ws_size,
                              hipStream_t stream){
  const float* x    = (const float*)d_in[0];
  const float* fcos = (const float*)d_in[3];
  const float* fsin = (const float*)d_in[4];
  const float* anw  = (const float*)d_in[5];
  const float* fnw  = (const float*)d_in[6];
  const float* wq   = (const float*)d_in[7];
  const float* wk   = (const float*)d_in[8];
  const float* wv_  = (const float*)d_in[9];
  const float* wo   = (const float*)d_in[10];
  const float* gw   = (const float*)d_in[11];
  const float* w1e  = (const float*)d_in[12];
  const float* w2e  = (const float*)d_in[13];
  const float* w3e  = (const float*)d_in[14];
  float* out = (float*)d_out;

  char* ws = (char*)d_ws;
  size_t off = 0;
  auto alloc = [&](size_t b)->void*{ void* p = ws + off; off += (b + 255) & ~(size_t)255; return p; };

  u16* wq_b = (u16*)alloc(2097152);
  u16* wk_b = (u16*)alloc(524288);
  u16* wv_b = (u16*)alloc(524288);
  u16* wo_b = (u16*)alloc(2097152);
  u16* w1_b = (u16*)alloc(46137344);
  u16* w2_b = (u16*)alloc(46137344);
  u16* w3_b = (u16*)alloc(46137344);
  u16* xn_b = (u16*)alloc(8388608);
  float* q_f = (float*)alloc(16777216);
  float* k_f = (float*)alloc(4194304);
  u16* q_b = (u16*)alloc(8388608);
  u16* k_b = (u16*)alloc(2097152);
  u16* v_b = (u16*)alloc(2097152);
  u16* at_b = (u16*)alloc(8388608);
  float* h_f = (float*)alloc(16777216);
  u16* hn_b = (u16*)alloc(8388608);
  float* hn_f = (float*)alloc(16777216);
  int2* tidx = (int2*)alloc(32768);
  float2* tw = (float2*)alloc(32768);
  int* pcnt = (int*)alloc(256);
  int* poff = (int*)alloc(256);
  int* pcur = (int*)alloc(256);
  int* meta = (int*)alloc(32768);
  float* pw = (float*)alloc(32768);
  u16* g_pool = (u16*)alloc(46137344);
  float* out_slot = (float*)alloc(33554432);

  // weight casts fp32 -> bf16
  cast_k<<<1024, 256, 0, stream>>>(wq, wq_b, 262144);
  cast_k<<<256, 256, 0, stream>>>(wk, wk_b, 65536);
  cast_k<<<256, 256, 0, stream>>>(wv_, wv_b, 65536);
  cast_k<<<1024, 256, 0, stream>>>(wo, wo_b, 262144);
  cast_k<<<22528, 256, 0, stream>>>(w1e, w1_b, 5767168);
  cast_k<<<22528, 256, 0, stream>>>(w2e, w2_b, 5767168);
  cast_k<<<22528, 256, 0, stream>>>(w3e, w3_b, 5767168);

  // attention input norm
  rmsnorm_k<<<4096, 256, 0, stream>>>(x, anw, xn_b, nullptr);

  // QKV projections
  gemm64<0><<<dim3(16,64), 256, 0, stream>>>(xn_b, wq_b, 4096, 1024, 1024, q_f, nullptr, nullptr);
  gemm64<0><<<dim3(4,64),  256, 0, stream>>>(xn_b, wk_b, 4096, 256, 1024, k_f, nullptr, nullptr);
  gemm64<1><<<dim3(4,64),  256, 0, stream>>>(xn_b, wv_b, 4096, 256, 1024, nullptr, v_b, nullptr);

  // RoPE (fp32 in, bf16 out)
  rope_k<<<8192, 256, 0, stream>>>(q_f, q_b, fcos, fsin, 16, 2097152);
  rope_k<<<2048, 256, 0, stream>>>(k_f, k_b, fcos, fsin, 4, 524288);

  // flash attention
  attn_k<<<dim3(16,16,4), 256, 0, stream>>>(q_b, k_b, v_b, at_b);

  // output projection + residual
  gemm64<2><<<dim3(16,64), 256, 0, stream>>>(at_b, wo_b, 4096, 1024, 1024, h_f, nullptr, x);

  // ffn norm (bf16 for experts, fp32 for gating)
  rmsnorm_k<<<4096, 256, 0, stream>>>(h_f, fnw, hn_b, hn_f);

  // routing
  init_k<<<1, 64, 0, stream>>>(pcnt);
  gate_top2<<<1024, 256, 0, stream>>>(hn_f, gw, tidx, tw, pcnt);
  offsets_k<<<1, 64, 0, stream>>>(pcnt, poff, pcur);
  scatter_k<<<16, 256, 0, stream>>>(tidx, tw, pcur, meta, pw);

  // expert GEMMs (compacted token pool, 8192 rows total)
  moe_up<<<dim3(44,64,8), 256, 0, stream>>>(hn_b, w1_b, w3_b, meta, poff, pcnt, g_pool);
  moe_down<<<dim3(16,64,8), 256, 0, stream>>>(g_pool, w2_b, meta, pw, poff, pcnt, out_slot);

  // final residual add: out = h + slot0 + slot1
  final_add<<<4096, 256, 0, stream>>>(h_f, out_slot, out_slot + 4194304, out, 1048576);
}

// Round 2
// 915.100 us; speedup vs baseline: 1.6139x; 1.6139x over previous
//
#include <hip/hip_runtime.h>
#include <hip/hip_bf16.h>

typedef unsigned short u16;
typedef __attribute__((ext_vector_type(8))) __bf16 bf16x8;
typedef __attribute__((ext_vector_type(4))) float floatx4;

__device__ __forceinline__ u16 f2bf(float f){
  union { float f; unsigned u; } v; v.f = f;
  unsigned u = v.u;
  return (u16)((u + 0x7fffu + ((u >> 16) & 1u)) >> 16);
}

__device__ __forceinline__ floatx4 mfma16(bf16x8 a, bf16x8 b, floatx4 c){
  return __builtin_amdgcn_mfma_f32_16x16x32_bf16(a, b, c, 0, 0, 0);
}

// async global->LDS, 16B per lane. LDS dest = wave-uniform base + lane*16.
__device__ __forceinline__ void gl16(const u16* g, u16* l){
  __builtin_amdgcn_global_load_lds((const __attribute__((address_space(1))) unsigned int*)g,
                                   (__attribute__((address_space(3))) unsigned int*)l, 16, 0, 0);
}

// ------------------------------ transpose-cast: src[R][C] fp32 -> dst[C][R] bf16 ------------------------------
__global__ __launch_bounds__(256) void tcast_k(const float* __restrict__ src, u16* __restrict__ dst,
                                               int R, int C){
  src += (size_t)blockIdx.z * (size_t)R * C;
  dst += (size_t)blockIdx.z * (size_t)R * C;
  __shared__ u16 tile[64][65];
  const int r0 = blockIdx.y*64, c0 = blockIdx.x*64;
  const int t = threadIdx.x;
  const int tr = t>>4, tc = (t&15)*4;
  #pragma unroll
  for (int i=0;i<4;++i){
    float4 v = *(const float4*)(src + (size_t)(r0+tr+i*16)*C + c0 + tc);
    tile[tr+i*16][tc]   = f2bf(v.x);
    tile[tr+i*16][tc+1] = f2bf(v.y);
    tile[tr+i*16][tc+2] = f2bf(v.z);
    tile[tr+i*16][tc+3] = f2bf(v.w);
  }
  __syncthreads();
  const int on = t>>3, ok = (t&7)*8;
  #pragma unroll
  for (int p=0;p<2;++p){
    int n = on + p*32;
    ushort u[8];
    #pragma unroll
    for (int j=0;j<8;++j) u[j] = tile[ok+j][n];
    *(uint4*)(dst + (size_t)(c0+n)*R + r0 + ok) = *(uint4*)u;
  }
}

// ------------------------------ elementwise ------------------------------
__global__ __launch_bounds__(256) void rmsnorm_k(const float* __restrict__ x, const float* __restrict__ w,
                                                 u16* __restrict__ ob){
  const int row = blockIdx.x, t = threadIdx.x;
  float4 v = ((const float4*)(x + (size_t)row*1024))[t];
  float ss = v.x*v.x + v.y*v.y + v.z*v.z + v.w*v.w;
  #pragma unroll
  for (int o=32;o>0;o>>=1) ss += __shfl_down(ss, o);
  __shared__ float red[4];
  if ((t&63)==0) red[t>>6]=ss;
  __syncthreads();
  float sc = rsqrtf((red[0]+red[1]+red[2]+red[3])*(1.0f/1024.0f) + 1e-5f);
  float4 wv = ((const float4*)w)[t];
  ushort4 q; q.x=f2bf(v.x*sc*wv.x); q.y=f2bf(v.y*sc*wv.y); q.z=f2bf(v.z*sc*wv.z); q.w=f2bf(v.w*sc*wv.w);
  ((ushort4*)(ob + (size_t)row*1024))[t] = q;
}

__global__ __launch_bounds__(256) void rope_k(const float* __restrict__ src, u16* __restrict__ dst,
                                              const float* __restrict__ cosb, const float* __restrict__ sinb,
                                              int NH, int n, int sld, int soff){
  int idx = blockIdx.x*256 + threadIdx.x;
  if (idx >= n) return;
  int i = idx & 31;
  int rest = idx >> 5;
  int h = rest % NH;
  int bs = rest / NH;
  int s = bs & 1023;
  float a = src[(size_t)bs*sld + soff + h*64 + 2*i];
  float b = src[(size_t)bs*sld + soff + h*64 + 2*i + 1];
  float c = cosb[s*32+i], sn = sinb[s*32+i];
  size_t p = (((size_t)bs*NH) + h)*64 + 2*i;
  dst[p]   = f2bf(a*c - b*sn);
  dst[p+1] = f2bf(a*sn + b*c);
}

__global__ __launch_bounds__(256) void vcast_k(const float* __restrict__ qkv, u16* __restrict__ vb){
  int idx = blockIdx.x*256 + threadIdx.x;   // 131072 total
  int row = idx >> 5, c8 = (idx & 31)*8;
  const float* s = qkv + (size_t)row*1536 + 1280 + c8;
  float4 v0 = *(const float4*)s, v1 = *(const float4*)(s+4);
  ushort u[8] = {f2bf(v0.x),f2bf(v0.y),f2bf(v0.z),f2bf(v0.w),f2bf(v1.x),f2bf(v1.y),f2bf(v1.z),f2bf(v1.w)};
  *(uint4*)(vb + (size_t)row*256 + c8) = *(uint4*)u;
}

// ------------------------------ m97-style 128x128 GEMM ------------------------------
// C[M,N] = A[M,K] @ Bt[N,K]^T, all bf16, swizzled global_load_lds staging.
// EPI: 0 = store fp32, 1 = store fp32 + resid
template<int EPI>
__global__ __launch_bounds__(256) void gemm128(const u16* __restrict__ A, const u16* __restrict__ Bt,
                                               int M, int N, int K,
                                               float* __restrict__ Cf, const float* __restrict__ resid){
  __shared__ u16 As[128*32];
  __shared__ u16 Bs[128*32];
  const int t = threadIdx.x;
  const int wave = t>>6, lane = t&63, lrow = lane&15, quad = lane>>4;
  const int wm = (wave&1)*64, wn = (wave>>1)*64;
  const int mbase = blockIdx.y*128, nbase = blockIdx.x*128;
  const int ca = wave*128 + lane;
  const int r0 = ca>>2;
  const int jsw = (ca&3) ^ ((r0 + (r0>>2))&3);
  const u16* a0 = A  + (size_t)(mbase + r0)*K + jsw*8;
  const u16* a1 = a0 + (size_t)16*K;
  const u16* b0 = Bt + (size_t)(nbase + r0)*K + jsw*8;
  const u16* b1 = b0 + (size_t)16*K;
  u16* lA = As + wave*1024;
  u16* lB = Bs + wave*1024;
  const int swz = (lrow + (lrow>>2)) & 3;
  floatx4 acc[4][4];
  #pragma unroll
  for (int i=0;i<4;++i)
  #pragma unroll
  for (int j=0;j<4;++j) acc[i][j] = floatx4{0.f,0.f,0.f,0.f};
  for (int k0=0;k0<K;k0+=32){
    __syncthreads();
    gl16(a0, lA); gl16(a1, lA+512);
    gl16(b0, lB); gl16(b1, lB+512);
    a0 += 32; a1 += 32; b0 += 32; b1 += 32;
    __syncthreads();
    bf16x8 af[4], bfr[4];
    #pragma unroll
    for (int mi=0;mi<4;++mi) af[mi]  = *(const bf16x8*)&As[(((wm+mi*16+lrow)<<2) + (quad^swz))*8];
    #pragma unroll
    for (int ni=0;ni<4;++ni) bfr[ni] = *(const bf16x8*)&Bs[(((wn+ni*16+lrow)<<2) + (quad^swz))*8];
    #pragma unroll
    for (int mi=0;mi<4;++mi)
    #pragma unroll
    for (int ni=0;ni<4;++ni) acc[mi][ni] = mfma16(af[mi], bfr[ni], acc[mi][ni]);
  }
  #pragma unroll
  for (int mi=0;mi<4;++mi)
  #pragma unroll
  for (int ni=0;ni<4;++ni)
  #pragma unroll
  for (int i=0;i<4;++i){
    int row = mbase + wm + mi*16 + quad*4 + i;
    int col = nbase + wn + ni*16 + lrow;
    float val = acc[mi][ni][i];
    if (EPI==1) val += resid[(size_t)row*N + col];
    Cf[(size_t)row*N + col] = val;
  }
}

// ------------------------------ flash attention (bf16 MFMA) ------------------------------
#define ATS 72
__global__ __launch_bounds__(256) void attn_k(const u16* __restrict__ qb, const u16* __restrict__ kb,
                                              const u16* __restrict__ vb, u16* __restrict__ ob){
  const int qt = blockIdx.x, h = blockIdx.y, b = blockIdx.z;
  const int kvh = h >> 2;
  __shared__ u16 Qs[64*ATS];
  __shared__ u16 Ks[64*ATS];
  __shared__ u16 Vt[64*ATS];
  __shared__ u16 Ps[4*16*ATS];
  const int t = threadIdx.x;
  const int wv = t>>6, lane = t&63, lrow = lane&15, quad = lane>>4;
  const int q0 = qt*64;
  const float NEG_INF = -__builtin_inff();
  {
    const int r = t>>2, c0 = (t&3)*16;
    const u16* src = qb + ((((size_t)(b*1024 + q0 + r))*16) + h)*64 + c0;
    *(uint4*)(&Qs[r*ATS + c0])     = *(const uint4*)(src);
    *(uint4*)(&Qs[r*ATS + c0 + 8]) = *(const uint4*)(src + 8);
  }
  floatx4 out[4];
  #pragma unroll
  for (int i=0;i<4;++i) out[i] = floatx4{0.f,0.f,0.f,0.f};
  float m_i[4], l_i[4];
  #pragma unroll
  for (int i=0;i<4;++i){ m_i[i] = NEG_INF; l_i[i] = 0.f; }

  for (int kt=0; kt<=qt; ++kt){
    const int k0 = kt*64;
    __syncthreads();
    {
      const int r = t>>2, c0 = (t&3)*16;
      const u16* src = kb + ((((size_t)(b*1024 + k0 + r))*4) + kvh)*64 + c0;
      *(uint4*)(&Ks[r*ATS + c0])     = *(const uint4*)(src);
      *(uint4*)(&Ks[r*ATS + c0 + 8]) = *(const uint4*)(src + 8);
    }
    {
      const int r = t>>3, c0 = (t&7)*8;
      #pragma unroll
      for (int half=0; half<2; ++half){
        int rr = r + half*32;
        uint4 v = *(const uint4*)(vb + ((((size_t)(b*1024 + k0 + rr))*4) + kvh)*64 + c0);
        const u16* s = (const u16*)&v;
        #pragma unroll
        for (int j=0;j<8;++j) Vt[(c0+j)*ATS + rr] = s[j];
      }
    }
    __syncthreads();
    floatx4 sc[4];
    #pragma unroll
    for (int i=0;i<4;++i) sc[i] = floatx4{0.f,0.f,0.f,0.f};
    #pragma unroll
    for (int ks=0; ks<2; ++ks){
      bf16x8 af = *(const bf16x8*)(&Qs[(wv*16+lrow)*ATS + ks*32 + quad*8]);
      #pragma unroll
      for (int nt=0;nt<4;++nt){
        bf16x8 bf = *(const bf16x8*)(&Ks[(nt*16+lrow)*ATS + ks*32 + quad*8]);
        sc[nt] = mfma16(af, bf, sc[nt]);
      }
    }
    const bool diag = (kt==qt);
    float rmax[4] = {NEG_INF,NEG_INF,NEG_INF,NEG_INF};
    #pragma unroll
    for (int nt=0;nt<4;++nt)
    #pragma unroll
    for (int i=0;i<4;++i){
      float s = sc[nt][i]*0.125f;
      if (diag && (nt*16+lrow > wv*16 + quad*4 + i)) s = NEG_INF;
      sc[nt][i] = s;
      rmax[i] = fmaxf(rmax[i], s);
    }
    #pragma unroll
    for (int o=1;o<16;o<<=1)
      #pragma unroll
      for (int i=0;i<4;++i) rmax[i] = fmaxf(rmax[i], __shfl_xor(rmax[i], o));
    float al[4], psum[4] = {0.f,0.f,0.f,0.f};
    #pragma unroll
    for (int i=0;i<4;++i){
      float mn = fmaxf(m_i[i], rmax[i]);
      al[i] = expf(m_i[i]-mn);
      m_i[i] = mn;
    }
    #pragma unroll
    for (int nt=0;nt<4;++nt)
    #pragma unroll
    for (int i=0;i<4;++i){
      float p = expf(sc[nt][i]-m_i[i]);
      sc[nt][i] = p;
      psum[i] += p;
    }
    #pragma unroll
    for (int o=1;o<16;o<<=1)
      #pragma unroll
      for (int i=0;i<4;++i) psum[i] += __shfl_xor(psum[i], o);
    #pragma unroll
    for (int i=0;i<4;++i) l_i[i] = l_i[i]*al[i] + psum[i];
    #pragma unroll
    for (int nt=0;nt<4;++nt)
      #pragma unroll
      for (int i=0;i<4;++i) out[nt][i] *= al[i];
    u16* Pw = &Ps[wv*16*ATS];
    #pragma unroll
    for (int nt=0;nt<4;++nt)
    #pragma unroll
    for (int i=0;i<4;++i)
      Pw[(quad*4+i)*ATS + nt*16 + lrow] = f2bf(sc[nt][i]);
    __syncthreads();
    #pragma unroll
    for (int ks=0; ks<2; ++ks){
      bf16x8 af = *(const bf16x8*)(&Pw[lrow*ATS + ks*32 + quad*8]);
      #pragma unroll
      for (int nt=0;nt<4;++nt){
        bf16x8 bf = *(const bf16x8*)(&Vt[(nt*16+lrow)*ATS + ks*32 + quad*8]);
        out[nt] = mfma16(af, bf, out[nt]);
      }
    }
  }
  #pragma unroll
  for (int nt=0;nt<4;++nt)
  #pragma unroll
  for (int i=0;i<4;++i){
    int row = q0 + wv*16 + quad*4 + i;
    float o = out[nt][i] / l_i[i];
    ob[((size_t)(b*1024 + row))*1024 + h*64 + nt*16 + lrow] = f2bf(o);
  }
}

// ------------------------------ MoE routing ------------------------------
__global__ void init_k(int* counts){ if (threadIdx.x < 8) counts[threadIdx.x] = 0; }

__global__ __launch_bounds__(256) void gate_top2(const float* __restrict__ h, const float* __restrict__ fnw,
                                                 const float* __restrict__ gw,
                                                 int2* __restrict__ tidx, float2* __restrict__ tw,
                                                 int* __restrict__ counts){
  const int token = blockIdx.x*4 + (threadIdx.x>>6);
  const int lane = threadIdx.x & 63;
  const float* xr = h + (size_t)token*1024;
  float ss = 0.f;
  float acc[8] = {0,0,0,0,0,0,0,0};
  for (int it=0; it<16; ++it){
    int d = lane + it*64;
    float xv = xr[d];
    ss += xv*xv;
    float xw = xv * fnw[d];
    const float4* g4 = (const float4*)(gw + d*8);
    float4 g0 = g4[0], g1 = g4[1];
    acc[0] += xw*g0.x; acc[1] += xw*g0.y; acc[2] += xw*g0.z; acc[3] += xw*g0.w;
    acc[4] += xw*g1.x; acc[5] += xw*g1.y; acc[6] += xw*g1.z; acc[7] += xw*g1.w;
  }
  #pragma unroll
  for (int o=1;o<64;o<<=1){
    ss += __shfl_xor(ss, o);
    #pragma unroll
    for (int e=0;e<8;++e) acc[e] += __shfl_xor(acc[e], o);
  }
  if (lane==0){
    // logits = acc[e] * rms_scale (w folded in already)
    int i0=0; float v0=acc[0];
    #pragma unroll
    for (int e=1;e<8;++e) if (acc[e] > v0){ v0=acc[e]; i0=e; }
    int i1=-1; float v1=-__builtin_inff();
    #pragma unroll
    for (int e=0;e<8;++e) if (e!=i0 && acc[e] > v1){ v1=acc[e]; i1=e; }
    float scl = rsqrtf(ss*(1.0f/1024.0f) + 1e-5f);
    float e2 = expf((v1 - v0)*scl);
    float w0 = 1.0f/(1.0f+e2);
    float w1 = e2/(1.0f+e2);
    int2 ii; ii.x=i0; ii.y=i1; tidx[token]=ii;
    float2 ww; ww.x=w0; ww.y=w1; tw[token]=ww;
    atomicAdd(&counts[i0],1);
    atomicAdd(&counts[i1],1);
  }
}

// 128-aligned per-expert offsets + tile worklist
__global__ void offsets_k(const int* __restrict__ counts, int* __restrict__ poff, int* __restrict__ pcur,
                          int* __restrict__ tileinfo, int* __restrict__ ntiles){
  if (threadIdx.x==0){
    int run=0, nt=0;
    for (int e=0;e<8;++e){
      poff[e]=run; pcur[e]=run;
      int c = counts[e];
      int tl = (c+127)>>7;
      for (int mt=0; mt<tl; ++mt) tileinfo[nt++] = (e<<16)|mt;
      run += tl<<7;
    }
    *ntiles = nt;
  }
}

__global__ __launch_bounds__(256) void scatter_k(const int2* __restrict__ tidx, const float2* __restrict__ tw,
                                                 int* __restrict__ pcur, int* __restrict__ meta,
                                                 float* __restrict__ pw){
  int t = blockIdx.x*256 + threadIdx.x;
  if (t >= 4096) return;
  int2 ii = tidx[t]; float2 ww = tw[t];
  int p0 = atomicAdd(&pcur[ii.x],1); meta[p0] = t*2;   pw[p0] = ww.x;
  int p1 = atomicAdd(&pcur[ii.y],1); meta[p1] = t*2+1; pw[p1] = ww.y;
}

// ------------------------------ MoE GEMMs (m97 structure) ------------------------------
// up: A[128 pool rows gathered] x {w1t,w3t}[64 cols each], silu-mul epilogue -> g_pool bf16
__global__ __launch_bounds__(256) void moe_up128(const u16* __restrict__ hn_bf,
        const u16* __restrict__ w1t, const u16* __restrict__ w3t,
        const int* __restrict__ meta, const int* __restrict__ poff, const int* __restrict__ pcnt,
        const int* __restrict__ tileinfo, const int* __restrict__ ntiles,
        u16* __restrict__ g_pool){
  const int y = blockIdx.y;
  if (y >= *ntiles) return;
  const int ti = tileinfo[y];
  const int e = ti>>16, mt = ti & 0xffff;
  const int base = poff[e], cnt = pcnt[e];
  const int nbase = blockIdx.x*64;
  __shared__ u16 As[128*32];
  __shared__ u16 B1s[64*32];
  __shared__ u16 B3s[64*32];
  const int t = threadIdx.x;
  const int wave = t>>6, lane = t&63, lrow = lane&15, quad = lane>>4;
  const int wm = (wave&1)*64, wn = (wave>>1)*32;
  // A staging (gathered rows via meta)
  const int ca = wave*128 + lane;
  const int r0 = ca>>2;
  const int jA = (ca&3) ^ ((r0 + (r0>>2))&3);
  const int ml0 = mt*128 + r0, ml1 = ml0 + 16;
  const int tok0 = (ml0 < cnt) ? (meta[base+ml0]>>1) : 0;
  const int tok1 = (ml1 < cnt) ? (meta[base+ml1]>>1) : 0;
  const u16* a0 = hn_bf + (size_t)tok0*1024 + jA*8;
  const u16* a1 = hn_bf + (size_t)tok1*1024 + jA*8;
  // B staging: 64x32 tile each, chunk = t
  const int rB = t>>2;
  const int jB = (t&3) ^ ((rB + (rB>>2))&3);
  const u16* b1p = w1t + (size_t)e*2816*1024 + (size_t)(nbase+rB)*1024 + jB*8;
  const u16* b3p = w3t + (size_t)e*2816*1024 + (size_t)(nbase+rB)*1024 + jB*8;
  u16* lA  = As  + wave*1024;
  u16* lB1 = B1s + wave*512;
  u16* lB3 = B3s + wave*512;
  const int swz = (lrow + (lrow>>2)) & 3;
  floatx4 a1c[4][2], a3c[4][2];
  #pragma unroll
  for (int i=0;i<4;++i)
  #pragma unroll
  for (int j=0;j<2;++j){ a1c[i][j]=floatx4{0.f,0.f,0.f,0.f}; a3c[i][j]=floatx4{0.f,0.f,0.f,0.f}; }
  for (int k0=0;k0<1024;k0+=32){
    __syncthreads();
    gl16(a0, lA); gl16(a1, lA+512);
    gl16(b1p, lB1); gl16(b3p, lB3);
    a0 += 32; a1 += 32; b1p += 32; b3p += 32;
    __syncthreads();
    bf16x8 af[4], b1f[2], b3f[2];
    #pragma unroll
    for (int mi=0;mi<4;++mi) af[mi] = *(const bf16x8*)&As[(((wm+mi*16+lrow)<<2) + (quad^swz))*8];
    #pragma unroll
    for (int ni=0;ni<2;++ni){
      b1f[ni] = *(const bf16x8*)&B1s[(((wn+ni*16+lrow)<<2) + (quad^swz))*8];
      b3f[ni] = *(const bf16x8*)&B3s[(((wn+ni*16+lrow)<<2) + (quad^swz))*8];
    }
    #pragma unroll
    for (int mi=0;mi<4;++mi)
    #pragma unroll
    for (int ni=0;ni<2;++ni){
      a1c[mi][ni] = mfma16(af[mi], b1f[ni], a1c[mi][ni]);
      a3c[mi][ni] = mfma16(af[mi], b3f[ni], a3c[mi][ni]);
    }
  }
  #pragma unroll
  for (int mi=0;mi<4;++mi)
  #pragma unroll
  for (int ni=0;ni<2;++ni)
  #pragma unroll
  for (int i=0;i<4;++i){
    int rit = wm + mi*16 + quad*4 + i;
    if (mt*128 + rit < cnt){
      int prow = base + mt*128 + rit;
      int col = nbase + wn + ni*16 + lrow;
      float x1 = a1c[mi][ni][i], x3 = a3c[mi][ni][i];
      float g = (x1 / (1.0f + expf(-x1))) * x3;
      g_pool[(size_t)prow*2816 + col] = f2bf(g);
    }
  }
}

// down: A = g_pool rows (contiguous), B = w2t, epilogue atomicAdd into out
__global__ __launch_bounds__(256) void moe_down128(const u16* __restrict__ g_pool, const u16* __restrict__ w2t,
        const int* __restrict__ meta, const float* __restrict__ pw,
        const int* __restrict__ poff, const int* __restrict__ pcnt,
        const int* __restrict__ tileinfo, const int* __restrict__ ntiles,
        float* __restrict__ out){
  const int y = blockIdx.y;
  if (y >= *ntiles) return;
  const int ti = tileinfo[y];
  const int e = ti>>16, mt = ti & 0xffff;
  const int base = poff[e], cnt = pcnt[e];
  const int nbase = blockIdx.x*128;
  __shared__ u16 As[128*32];
  __shared__ u16 Bs[128*32];
  const int t = threadIdx.x;
  const int wave = t>>6, lane = t&63, lrow = lane&15, quad = lane>>4;
  const int wm = (wave&1)*64, wn = (wave>>1)*64;
  const int ca = wave*128 + lane;
  const int r0 = ca>>2;
  const int jsw = (ca&3) ^ ((r0 + (r0>>2))&3);
  const u16* a0 = g_pool + (size_t)(base + mt*128 + r0)*2816 + jsw*8;
  const u16* a1 = a0 + (size_t)16*2816;
  const u16* b0 = w2t + (size_t)e*1024*2816 + (size_t)(nbase + r0)*2816 + jsw*8;
  const u16* b1 = b0 + (size_t)16*2816;
  u16* lA = As + wave*1024;
  u16* lB = Bs + wave*1024;
  const int swz = (lrow + (lrow>>2)) & 3;
  floatx4 acc[4][4];
  #pragma unroll
  for (int i=0;i<4;++i)
  #pragma unroll
  for (int j=0;j<4;++j) acc[i][j] = floatx4{0.f,0.f,0.f,0.f};
  for (int k0=0;k0<2816;k0+=32){
    __syncthreads();
    gl16(a0, lA); gl16(a1, lA+512);
    gl16(b0, lB); gl16(b1, lB+512);
    a0 += 32; a1 += 32; b0 += 32; b1 += 32;
    __syncthreads();
    bf16x8 af[4], bfr[4];
    #pragma unroll
    for (int mi=0;mi<4;++mi) af[mi]  = *(const bf16x8*)&As[(((wm+mi*16+lrow)<<2) + (quad^swz))*8];
    #pragma unroll
    for (int ni=0;ni<4;++ni) bfr[ni] = *(const bf16x8*)&Bs[(((wn+ni*16+lrow)<<2) + (quad^swz))*8];
    #pragma unroll
    for (int mi=0;mi<4;++mi)
    #pragma unroll
    for (int ni=0;ni<4;++ni) acc[mi][ni] = mfma16(af[mi], bfr[ni], acc[mi][ni]);
  }
  #pragma unroll
  for (int mi=0;mi<4;++mi)
  #pragma unroll
  for (int ni=0;ni<4;++ni)
  #pragma unroll
  for (int i=0;i<4;++i){
    int ml = mt*128 + wm + mi*16 + quad*4 + i;
    if (ml < cnt){
      int mm = meta[base+ml];
      int token = mm>>1;
      float wgt = pw[base+ml];
      int col = nbase + wn + ni*16 + lrow;
      atomicAdd(&out[(size_t)token*1024 + col], wgt*acc[mi][ni][i]);
    }
  }
}

// ------------------------------ launcher ------------------------------
extern "C" void kernel_launch(void* const* d_in, const int* in_sizes, int n_in,
                              void* d_out, int out_size, void* d_ws, size_t ws_size,
                              hipStream_t stream){
  const float* x    = (const float*)d_in[0];
  const float* fcos = (const float*)d_in[3];
  const float* fsin = (const float*)d_in[4];
  const float* anw  = (const float*)d_in[5];
  const float* fnw  = (const float*)d_in[6];
  const float* wq   = (const float*)d_in[7];
  const float* wk   = (const float*)d_in[8];
  const float* wv_  = (const float*)d_in[9];
  const float* wo   = (const float*)d_in[10];
  const float* gw   = (const float*)d_in[11];
  const float* w1e  = (const float*)d_in[12];
  const float* w2e  = (const float*)d_in[13];
  const float* w3e  = (const float*)d_in[14];
  float* out = (float*)d_out;

  char* ws = (char*)d_ws;
  size_t off = 0;
  auto alloc = [&](size_t b)->void*{ void* p = ws + off; off += (b + 255) & ~(size_t)255; return p; };

  u16* wqkv_t = (u16*)alloc(3145728);     // [1536][1024] bf16 (wq^T | wk^T | wv^T)
  u16* wo_t   = (u16*)alloc(2097152);     // [1024][1024]
  u16* w1t    = (u16*)alloc(46137344);    // [8][2816][1024]
  u16* w3t    = (u16*)alloc(46137344);
  u16* w2t    = (u16*)alloc(46137344);    // [8][1024][2816]
  u16* xn_b   = (u16*)alloc(8388608);
  float* qkv_f= (float*)alloc(25165824);  // [4096][1536]
  u16* q_b    = (u16*)alloc(8388608);
  u16* k_b    = (u16*)alloc(2097152);
  u16* v_b    = (u16*)alloc(2097152);
  u16* at_b   = (u16*)alloc(8388608);
  float* h_f  = (float*)alloc(16777216);
  u16* hn_b   = (u16*)alloc(8388608);
  int2* tidx  = (int2*)alloc(32768);
  float2* tw  = (float2*)alloc(32768);
  int* pcnt   = (int*)alloc(256);
  int* poff   = (int*)alloc(256);
  int* pcur   = (int*)alloc(256);
  int* tinfo  = (int*)alloc(512);
  int* ntl    = (int*)alloc(256);
  int* meta   = (int*)alloc(37376);       // 9344 slots
  float* pw   = (float*)alloc(37376);
  u16* g_pool = (u16*)alloc(52625408);    // 9344 x 2816 bf16

  // transpose-cast weights (fp32 [K][N] -> bf16 [N][K])
  tcast_k<<<dim3(16,16,1), 256, 0, stream>>>(wq,  wqkv_t,            1024, 1024);
  tcast_k<<<dim3(4,16,1),  256, 0, stream>>>(wk,  wqkv_t + 1048576,  1024, 256);
  tcast_k<<<dim3(4,16,1),  256, 0, stream>>>(wv_, wqkv_t + 1310720,  1024, 256);
  tcast_k<<<dim3(16,16,1), 256, 0, stream>>>(wo,  wo_t,              1024, 1024);
  tcast_k<<<dim3(44,16,8), 256, 0, stream>>>(w1e, w1t,               1024, 2816);
  tcast_k<<<dim3(44,16,8), 256, 0, stream>>>(w3e, w3t,               1024, 2816);
  tcast_k<<<dim3(16,44,8), 256, 0, stream>>>(w2e, w2t,               2816, 1024);

  // attention input norm
  rmsnorm_k<<<4096, 256, 0, stream>>>(x, anw, xn_b);

  // fused QKV projection: [4096,1024] x [1536,1024]^T -> fp32 [4096][1536]
  gemm128<0><<<dim3(12,32), 256, 0, stream>>>(xn_b, wqkv_t, 4096, 1536, 1024, qkv_f, nullptr);

  // RoPE q,k + cast v
  rope_k<<<8192, 256, 0, stream>>>(qkv_f, q_b, fcos, fsin, 16, 2097152, 1536, 0);
  rope_k<<<2048, 256, 0, stream>>>(qkv_f, k_b, fcos, fsin, 4,  524288, 1536, 1024);
  vcast_k<<<512, 256, 0, stream>>>(qkv_f, v_b);

  // flash attention
  attn_k<<<dim3(16,16,4), 256, 0, stream>>>(q_b, k_b, v_b, at_b);

  // output projection + residual -> h
  gemm128<1><<<dim3(8,32), 256, 0, stream>>>(at_b, wo_t, 4096, 1024, 1024, h_f, x);

  // ffn norm (bf16 for experts)
  rmsnorm_k<<<4096, 256, 0, stream>>>(h_f, fnw, hn_b);

  // routing (gating reads h_f fp32 + fnw, folds rms scale in)
  init_k<<<1, 64, 0, stream>>>(pcnt);
  gate_top2<<<1024, 256, 0, stream>>>(h_f, fnw, gw, tidx, tw, pcnt);
  offsets_k<<<1, 64, 0, stream>>>(pcnt, poff, pcur, tinfo, ntl);
  scatter_k<<<16, 256, 0, stream>>>(tidx, tw, pcur, meta, pw);

  // out = h  (moe_down atomic-accumulates on top)
  hipMemcpyAsync(out, h_f, 16777216, hipMemcpyDeviceToDevice, stream);

  // expert GEMMs
  moe_up128<<<dim3(44,72), 256, 0, stream>>>(hn_b, w1t, w3t, meta, poff, pcnt, tinfo, ntl, g_pool);
  moe_down128<<<dim3(8,72), 256, 0, stream>>>(g_pool, w2t, meta, pw, poff, pcnt, tinfo, ntl, out);
}

// Round 3
// 887.909 us; speedup vs baseline: 1.6633x; 1.0306x over previous
//
#include <hip/hip_runtime.h>
#include <hip/hip_bf16.h>

typedef unsigned short u16;
typedef __attribute__((ext_vector_type(8))) __bf16 bf16x8;
typedef __attribute__((ext_vector_type(4))) float floatx4;

__device__ __forceinline__ u16 f2bf(float f){
  union { float f; unsigned u; } v; v.f = f;
  unsigned u = v.u;
  return (u16)((u + 0x7fffu + ((u >> 16) & 1u)) >> 16);
}

__device__ __forceinline__ floatx4 mfma16(bf16x8 a, bf16x8 b, floatx4 c){
  return __builtin_amdgcn_mfma_f32_16x16x32_bf16(a, b, c, 0, 0, 0);
}

// async global->LDS, 16B per lane. LDS dest = wave-uniform base + lane*16.
__device__ __forceinline__ void gl16(const u16* g, u16* l){
  __builtin_amdgcn_global_load_lds((const __attribute__((address_space(1))) unsigned int*)g,
                                   (__attribute__((address_space(3))) unsigned int*)l, 16, 0, 0);
}

// ------------------------------ transpose-cast: src[R][C] fp32 -> dst[C][R] bf16 ------------------------------
__global__ __launch_bounds__(256) void tcast_k(const float* __restrict__ src, u16* __restrict__ dst,
                                               int R, int C){
  src += (size_t)blockIdx.z * (size_t)R * C;
  dst += (size_t)blockIdx.z * (size_t)R * C;
  __shared__ u16 tile[64][65];
  const int r0 = blockIdx.y*64, c0 = blockIdx.x*64;
  const int t = threadIdx.x;
  const int tr = t>>4, tc = (t&15)*4;
  #pragma unroll
  for (int i=0;i<4;++i){
    float4 v = *(const float4*)(src + (size_t)(r0+tr+i*16)*C + c0 + tc);
    tile[tr+i*16][tc]   = f2bf(v.x);
    tile[tr+i*16][tc+1] = f2bf(v.y);
    tile[tr+i*16][tc+2] = f2bf(v.z);
    tile[tr+i*16][tc+3] = f2bf(v.w);
  }
  __syncthreads();
  const int on = t>>3, ok = (t&7)*8;
  #pragma unroll
  for (int p=0;p<2;++p){
    int n = on + p*32;
    ushort u[8];
    #pragma unroll
    for (int j=0;j<8;++j) u[j] = tile[ok+j][n];
    *(uint4*)(dst + (size_t)(c0+n)*R + r0 + ok) = *(uint4*)u;
  }
}

// ------------------------------ elementwise ------------------------------
__global__ __launch_bounds__(256) void rmsnorm_k(const float* __restrict__ x, const float* __restrict__ w,
                                                 u16* __restrict__ ob){
  const int row = blockIdx.x, t = threadIdx.x;
  float4 v = ((const float4*)(x + (size_t)row*1024))[t];
  float ss = v.x*v.x + v.y*v.y + v.z*v.z + v.w*v.w;
  #pragma unroll
  for (int o=32;o>0;o>>=1) ss += __shfl_down(ss, o);
  __shared__ float red[4];
  if ((t&63)==0) red[t>>6]=ss;
  __syncthreads();
  float sc = rsqrtf((red[0]+red[1]+red[2]+red[3])*(1.0f/1024.0f) + 1e-5f);
  float4 wv = ((const float4*)w)[t];
  ushort4 q; q.x=f2bf(v.x*sc*wv.x); q.y=f2bf(v.y*sc*wv.y); q.z=f2bf(v.z*sc*wv.z); q.w=f2bf(v.w*sc*wv.w);
  ((ushort4*)(ob + (size_t)row*1024))[t] = q;
}

__global__ __launch_bounds__(256) void rope_k(const float* __restrict__ src, u16* __restrict__ dst,
                                              const float* __restrict__ cosb, const float* __restrict__ sinb,
                                              int NH, int n, int sld, int soff){
  int idx = blockIdx.x*256 + threadIdx.x;
  if (idx >= n) return;
  int i = idx & 31;
  int rest = idx >> 5;
  int h = rest % NH;
  int bs = rest / NH;
  int s = bs & 1023;
  float a = src[(size_t)bs*sld + soff + h*64 + 2*i];
  float b = src[(size_t)bs*sld + soff + h*64 + 2*i + 1];
  float c = cosb[s*32+i], sn = sinb[s*32+i];
  size_t p = (((size_t)bs*NH) + h)*64 + 2*i;
  dst[p]   = f2bf(a*c - b*sn);
  dst[p+1] = f2bf(a*sn + b*c);
}

__global__ __launch_bounds__(256) void vcast_k(const float* __restrict__ qkv, u16* __restrict__ vb){
  int idx = blockIdx.x*256 + threadIdx.x;   // 131072 total
  int row = idx >> 5, c8 = (idx & 31)*8;
  const float* s = qkv + (size_t)row*1536 + 1280 + c8;
  float4 v0 = *(const float4*)s, v1 = *(const float4*)(s+4);
  ushort u[8] = {f2bf(v0.x),f2bf(v0.y),f2bf(v0.z),f2bf(v0.w),f2bf(v1.x),f2bf(v1.y),f2bf(v1.z),f2bf(v1.w)};
  *(uint4*)(vb + (size_t)row*256 + c8) = *(uint4*)u;
}

__global__ __launch_bounds__(256) void final_add(const float* __restrict__ h, const float* __restrict__ s0,
                                                 const float* __restrict__ s1, float* __restrict__ out, int n4){
  int i = blockIdx.x*256 + threadIdx.x;
  if (i >= n4) return;
  float4 a = ((const float4*)h)[i], b = ((const float4*)s0)[i], c = ((const float4*)s1)[i];
  float4 o; o.x=a.x+b.x+c.x; o.y=a.y+b.y+c.y; o.z=a.z+b.z+c.z; o.w=a.w+b.w+c.w;
  ((float4*)out)[i] = o;
}

// ------------------------------ m97-style 128x128 GEMM ------------------------------
// C[M,N] = A[M,K] @ Bt[N,K]^T, all bf16, swizzled global_load_lds staging.
// EPI: 0 = store fp32, 1 = store fp32 + resid
template<int EPI>
__global__ __launch_bounds__(256) void gemm128(const u16* __restrict__ A, const u16* __restrict__ Bt,
                                               int M, int N, int K,
                                               float* __restrict__ Cf, const float* __restrict__ resid){
  __shared__ u16 As[128*32];
  __shared__ u16 Bs[128*32];
  const int t = threadIdx.x;
  const int wave = t>>6, lane = t&63, lrow = lane&15, quad = lane>>4;
  const int wm = (wave&1)*64, wn = (wave>>1)*64;
  const int mbase = blockIdx.y*128, nbase = blockIdx.x*128;
  const int ca = wave*128 + lane;
  const int r0 = ca>>2;
  const int jsw = (ca&3) ^ ((r0 + (r0>>2))&3);
  const u16* a0 = A  + (size_t)(mbase + r0)*K + jsw*8;
  const u16* a1 = a0 + (size_t)16*K;
  const u16* b0 = Bt + (size_t)(nbase + r0)*K + jsw*8;
  const u16* b1 = b0 + (size_t)16*K;
  u16* lA = As + wave*1024;
  u16* lB = Bs + wave*1024;
  const int swz = (lrow + (lrow>>2)) & 3;
  floatx4 acc[4][4];
  #pragma unroll
  for (int i=0;i<4;++i)
  #pragma unroll
  for (int j=0;j<4;++j) acc[i][j] = floatx4{0.f,0.f,0.f,0.f};
  for (int k0=0;k0<K;k0+=32){
    __syncthreads();
    gl16(a0, lA); gl16(a1, lA+512);
    gl16(b0, lB); gl16(b1, lB+512);
    a0 += 32; a1 += 32; b0 += 32; b1 += 32;
    __syncthreads();
    bf16x8 af[4], bfr[4];
    #pragma unroll
    for (int mi=0;mi<4;++mi) af[mi]  = *(const bf16x8*)&As[(((wm+mi*16+lrow)<<2) + (quad^swz))*8];
    #pragma unroll
    for (int ni=0;ni<4;++ni) bfr[ni] = *(const bf16x8*)&Bs[(((wn+ni*16+lrow)<<2) + (quad^swz))*8];
    #pragma unroll
    for (int mi=0;mi<4;++mi)
    #pragma unroll
    for (int ni=0;ni<4;++ni) acc[mi][ni] = mfma16(af[mi], bfr[ni], acc[mi][ni]);
  }
  #pragma unroll
  for (int mi=0;mi<4;++mi)
  #pragma unroll
  for (int ni=0;ni<4;++ni)
  #pragma unroll
  for (int i=0;i<4;++i){
    int row = mbase + wm + mi*16 + quad*4 + i;
    int col = nbase + wn + ni*16 + lrow;
    float val = acc[mi][ni][i];
    if (EPI==1) val += resid[(size_t)row*N + col];
    Cf[(size_t)row*N + col] = val;
  }
}

// ------------------------------ flash attention, paired q-tiles ------------------------------
#define ATS 72

__device__ __forceinline__ void qk_softmax(int kt, int qt, const u16* Qs, const u16* Ks, u16* Ps,
                                           floatx4* out, float* m_i, float* l_i,
                                           int wv, int lrow, int quad){
  const float NEG_INF = -__builtin_inff();
  floatx4 sc[4];
  #pragma unroll
  for (int i=0;i<4;++i) sc[i] = floatx4{0.f,0.f,0.f,0.f};
  #pragma unroll
  for (int ks=0; ks<2; ++ks){
    bf16x8 af = *(const bf16x8*)&Qs[(wv*16+lrow)*ATS + ks*32 + quad*8];
    #pragma unroll
    for (int nt=0;nt<4;++nt){
      bf16x8 bf = *(const bf16x8*)&Ks[(nt*16+lrow)*ATS + ks*32 + quad*8];
      sc[nt] = mfma16(af, bf, sc[nt]);
    }
  }
  const bool diag = (kt==qt);
  float rmax[4] = {NEG_INF,NEG_INF,NEG_INF,NEG_INF};
  #pragma unroll
  for (int nt=0;nt<4;++nt)
  #pragma unroll
  for (int i=0;i<4;++i){
    float s = sc[nt][i]*0.125f;
    if (diag && (nt*16+lrow > wv*16 + quad*4 + i)) s = NEG_INF;
    sc[nt][i] = s;
    rmax[i] = fmaxf(rmax[i], s);
  }
  #pragma unroll
  for (int o=1;o<16;o<<=1)
    #pragma unroll
    for (int i=0;i<4;++i) rmax[i] = fmaxf(rmax[i], __shfl_xor(rmax[i], o));
  float al[4], psum[4] = {0.f,0.f,0.f,0.f};
  #pragma unroll
  for (int i=0;i<4;++i){
    float mn = fmaxf(m_i[i], rmax[i]);
    al[i] = expf(m_i[i]-mn);
    m_i[i] = mn;
  }
  #pragma unroll
  for (int nt=0;nt<4;++nt)
  #pragma unroll
  for (int i=0;i<4;++i){
    float p = expf(sc[nt][i]-m_i[i]);
    sc[nt][i] = p;
    psum[i] += p;
  }
  #pragma unroll
  for (int o=1;o<16;o<<=1)
    #pragma unroll
    for (int i=0;i<4;++i) psum[i] += __shfl_xor(psum[i], o);
  #pragma unroll
  for (int i=0;i<4;++i) l_i[i] = l_i[i]*al[i] + psum[i];
  #pragma unroll
  for (int nt=0;nt<4;++nt)
    #pragma unroll
    for (int i=0;i<4;++i) out[nt][i] *= al[i];
  u16* Pw = Ps + wv*16*ATS;
  #pragma unroll
  for (int nt=0;nt<4;++nt)
  #pragma unroll
  for (int i=0;i<4;++i)
    Pw[(quad*4+i)*ATS + nt*16 + lrow] = f2bf(sc[nt][i]);
}

__device__ __forceinline__ void pv_acc(const u16* Ps, const u16* Vt, floatx4* out,
                                       int wv, int lrow, int quad){
  const u16* Pw = Ps + wv*16*ATS;
  #pragma unroll
  for (int ks=0; ks<2; ++ks){
    bf16x8 af = *(const bf16x8*)&Pw[lrow*ATS + ks*32 + quad*8];
    #pragma unroll
    for (int nt=0;nt<4;++nt){
      bf16x8 bf = *(const bf16x8*)&Vt[(nt*16+lrow)*ATS + ks*32 + quad*8];
      out[nt] = mfma16(af, bf, out[nt]);
    }
  }
}

// block bx handles q-tiles bx and 15-bx: uniform 17 kt-iterations, K/V staged once.
__global__ __launch_bounds__(256) void attn2_k(const u16* __restrict__ qb, const u16* __restrict__ kb,
                                               const u16* __restrict__ vb, u16* __restrict__ ob){
  const int bx = blockIdx.x, h = blockIdx.y, b = blockIdx.z;
  const int qtA = bx, qtB = 15 - bx;
  const int kvh = h >> 2;
  __shared__ u16 QsA[64*ATS], QsB[64*ATS], Ks[64*ATS], Vt[64*ATS], PsA[64*ATS], PsB[64*ATS];
  const int t = threadIdx.x;
  const int wv = t>>6, lane = t&63, lrow = lane&15, quad = lane>>4;
  const float NEG_INF = -__builtin_inff();
  {
    const int r = t>>2, c0 = (t&3)*16;
    const u16* sA = qb + ((((size_t)(b*1024 + qtA*64 + r))*16) + h)*64 + c0;
    *(uint4*)(&QsA[r*ATS + c0])     = *(const uint4*)(sA);
    *(uint4*)(&QsA[r*ATS + c0 + 8]) = *(const uint4*)(sA + 8);
    const u16* sB = qb + ((((size_t)(b*1024 + qtB*64 + r))*16) + h)*64 + c0;
    *(uint4*)(&QsB[r*ATS + c0])     = *(const uint4*)(sB);
    *(uint4*)(&QsB[r*ATS + c0 + 8]) = *(const uint4*)(sB + 8);
  }
  floatx4 outA[4], outB[4];
  float mA[4], lA[4], mB[4], lB[4];
  #pragma unroll
  for (int i=0;i<4;++i){
    outA[i] = floatx4{0.f,0.f,0.f,0.f}; outB[i] = floatx4{0.f,0.f,0.f,0.f};
    mA[i]=NEG_INF; lA[i]=0.f; mB[i]=NEG_INF; lB[i]=0.f;
  }
  for (int kt=0; kt<=qtB; ++kt){
    const int k0 = kt*64;
    __syncthreads();
    {
      const int r = t>>2, c0 = (t&3)*16;
      const u16* src = kb + ((((size_t)(b*1024 + k0 + r))*4) + kvh)*64 + c0;
      *(uint4*)(&Ks[r*ATS + c0])     = *(const uint4*)(src);
      *(uint4*)(&Ks[r*ATS + c0 + 8]) = *(const uint4*)(src + 8);
    }
    {
      const int r = t>>3, m = t&7, c0 = m*8;
      #pragma unroll
      for (int half=0; half<2; ++half){
        int rr = r + half*32;
        uint4 v = *(const uint4*)(vb + ((((size_t)(b*1024 + k0 + rr))*4) + kvh)*64 + c0);
        const u16* s = (const u16*)&v;
        #pragma unroll
        for (int j=0;j<8;++j){
          int jj = (j + m) & 7;                      // rotate: conflict-free banks
          Vt[(c0+jj)*ATS + rr] = s[jj];
        }
      }
    }
    __syncthreads();
    const bool doA = (kt <= qtA);
    if (doA) qk_softmax(kt, qtA, QsA, Ks, PsA, outA, mA, lA, wv, lrow, quad);
    qk_softmax(kt, qtB, QsB, Ks, PsB, outB, mB, lB, wv, lrow, quad);
    __syncthreads();
    if (doA) pv_acc(PsA, Vt, outA, wv, lrow, quad);
    pv_acc(PsB, Vt, outB, wv, lrow, quad);
  }
  #pragma unroll
  for (int nt=0;nt<4;++nt)
  #pragma unroll
  for (int i=0;i<4;++i){
    int rA = qtA*64 + wv*16 + quad*4 + i;
    int rB = qtB*64 + wv*16 + quad*4 + i;
    ob[((size_t)(b*1024 + rA))*1024 + h*64 + nt*16 + lrow] = f2bf(outA[nt][i] / lA[i]);
    ob[((size_t)(b*1024 + rB))*1024 + h*64 + nt*16 + lrow] = f2bf(outB[nt][i] / lB[i]);
  }
}

// ------------------------------ MoE routing ------------------------------
__global__ void init_k(int* counts){ if (threadIdx.x < 8) counts[threadIdx.x] = 0; }

__global__ __launch_bounds__(256) void gate_top2(const float* __restrict__ h, const float* __restrict__ fnw,
                                                 const float* __restrict__ gw,
                                                 int2* __restrict__ tidx, float2* __restrict__ tw,
                                                 int* __restrict__ counts){
  const int token = blockIdx.x*4 + (threadIdx.x>>6);
  const int lane = threadIdx.x & 63;
  const float* xr = h + (size_t)token*1024;
  float ss = 0.f;
  float acc[8] = {0,0,0,0,0,0,0,0};
  for (int it=0; it<16; ++it){
    int d = lane + it*64;
    float xv = xr[d];
    ss += xv*xv;
    float xw = xv * fnw[d];
    const float4* g4 = (const float4*)(gw + d*8);
    float4 g0 = g4[0], g1 = g4[1];
    acc[0] += xw*g0.x; acc[1] += xw*g0.y; acc[2] += xw*g0.z; acc[3] += xw*g0.w;
    acc[4] += xw*g1.x; acc[5] += xw*g1.y; acc[6] += xw*g1.z; acc[7] += xw*g1.w;
  }
  #pragma unroll
  for (int o=1;o<64;o<<=1){
    ss += __shfl_xor(ss, o);
    #pragma unroll
    for (int e=0;e<8;++e) acc[e] += __shfl_xor(acc[e], o);
  }
  if (lane==0){
    int i0=0; float v0=acc[0];
    #pragma unroll
    for (int e=1;e<8;++e) if (acc[e] > v0){ v0=acc[e]; i0=e; }
    int i1=-1; float v1=-__builtin_inff();
    #pragma unroll
    for (int e=0;e<8;++e) if (e!=i0 && acc[e] > v1){ v1=acc[e]; i1=e; }
    float scl = rsqrtf(ss*(1.0f/1024.0f) + 1e-5f);
    float e2 = expf((v1 - v0)*scl);
    float w0 = 1.0f/(1.0f+e2);
    float w1 = e2/(1.0f+e2);
    int2 ii; ii.x=i0; ii.y=i1; tidx[token]=ii;
    float2 ww; ww.x=w0; ww.y=w1; tw[token]=ww;
    atomicAdd(&counts[i0],1);
    atomicAdd(&counts[i1],1);
  }
}

__global__ void offsets_k(const int* __restrict__ counts, int* __restrict__ poff, int* __restrict__ pcur,
                          int* __restrict__ tileinfo, int* __restrict__ ntiles){
  if (threadIdx.x==0){
    int run=0, nt=0;
    for (int e=0;e<8;++e){
      poff[e]=run; pcur[e]=run;
      int c = counts[e];
      int tl = (c+127)>>7;
      for (int mt=0; mt<tl; ++mt) tileinfo[nt++] = (e<<16)|mt;
      run += tl<<7;
    }
    *ntiles = nt;
  }
}

__global__ __launch_bounds__(256) void scatter_k(const int2* __restrict__ tidx, const float2* __restrict__ tw,
                                                 int* __restrict__ pcur, int* __restrict__ meta,
                                                 float* __restrict__ pw){
  int t = blockIdx.x*256 + threadIdx.x;
  if (t >= 4096) return;
  int2 ii = tidx[t]; float2 ww = tw[t];
  int p0 = atomicAdd(&pcur[ii.x],1); meta[p0] = t*2;   pw[p0] = ww.x;
  int p1 = atomicAdd(&pcur[ii.y],1); meta[p1] = t*2+1; pw[p1] = ww.y;
}

// ------------------------------ MoE GEMMs (m97 structure) ------------------------------
__global__ __launch_bounds__(256) void moe_up128(const u16* __restrict__ hn_bf,
        const u16* __restrict__ w1t, const u16* __restrict__ w3t,
        const int* __restrict__ meta, const int* __restrict__ poff, const int* __restrict__ pcnt,
        const int* __restrict__ tileinfo, const int* __restrict__ ntiles,
        u16* __restrict__ g_pool){
  const int y = blockIdx.y;
  if (y >= *ntiles) return;
  const int ti = tileinfo[y];
  const int e = ti>>16, mt = ti & 0xffff;
  const int base = poff[e], cnt = pcnt[e];
  const int nbase = blockIdx.x*64;
  __shared__ u16 As[128*32];
  __shared__ u16 B1s[64*32];
  __shared__ u16 B3s[64*32];
  const int t = threadIdx.x;
  const int wave = t>>6, lane = t&63, lrow = lane&15, quad = lane>>4;
  const int wm = (wave&1)*64, wn = (wave>>1)*32;
  const int ca = wave*128 + lane;
  const int r0 = ca>>2;
  const int jA = (ca&3) ^ ((r0 + (r0>>2))&3);
  const int ml0 = mt*128 + r0, ml1 = ml0 + 16;
  const int tok0 = (ml0 < cnt) ? (meta[base+ml0]>>1) : 0;
  const int tok1 = (ml1 < cnt) ? (meta[base+ml1]>>1) : 0;
  const u16* a0 = hn_bf + (size_t)tok0*1024 + jA*8;
  const u16* a1 = hn_bf + (size_t)tok1*1024 + jA*8;
  const int rB = t>>2;
  const int jB = (t&3) ^ ((rB + (rB>>2))&3);
  const u16* b1p = w1t + (size_t)e*2816*1024 + (size_t)(nbase+rB)*1024 + jB*8;
  const u16* b3p = w3t + (size_t)e*2816*1024 + (size_t)(nbase+rB)*1024 + jB*8;
  u16* lA  = As  + wave*1024;
  u16* lB1 = B1s + wave*512;
  u16* lB3 = B3s + wave*512;
  const int swz = (lrow + (lrow>>2)) & 3;
  floatx4 a1c[4][2], a3c[4][2];
  #pragma unroll
  for (int i=0;i<4;++i)
  #pragma unroll
  for (int j=0;j<2;++j){ a1c[i][j]=floatx4{0.f,0.f,0.f,0.f}; a3c[i][j]=floatx4{0.f,0.f,0.f,0.f}; }
  for (int k0=0;k0<1024;k0+=32){
    __syncthreads();
    gl16(a0, lA); gl16(a1, lA+512);
    gl16(b1p, lB1); gl16(b3p, lB3);
    a0 += 32; a1 += 32; b1p += 32; b3p += 32;
    __syncthreads();
    bf16x8 af[4], b1f[2], b3f[2];
    #pragma unroll
    for (int mi=0;mi<4;++mi) af[mi] = *(const bf16x8*)&As[(((wm+mi*16+lrow)<<2) + (quad^swz))*8];
    #pragma unroll
    for (int ni=0;ni<2;++ni){
      b1f[ni] = *(const bf16x8*)&B1s[(((wn+ni*16+lrow)<<2) + (quad^swz))*8];
      b3f[ni] = *(const bf16x8*)&B3s[(((wn+ni*16+lrow)<<2) + (quad^swz))*8];
    }
    #pragma unroll
    for (int mi=0;mi<4;++mi)
    #pragma unroll
    for (int ni=0;ni<2;++ni){
      a1c[mi][ni] = mfma16(af[mi], b1f[ni], a1c[mi][ni]);
      a3c[mi][ni] = mfma16(af[mi], b3f[ni], a3c[mi][ni]);
    }
  }
  #pragma unroll
  for (int mi=0;mi<4;++mi)
  #pragma unroll
  for (int ni=0;ni<2;++ni)
  #pragma unroll
  for (int i=0;i<4;++i){
    int rit = wm + mi*16 + quad*4 + i;
    if (mt*128 + rit < cnt){
      int prow = base + mt*128 + rit;
      int col = nbase + wn + ni*16 + lrow;
      float x1 = a1c[mi][ni][i], x3 = a3c[mi][ni][i];
      float g = (x1 / (1.0f + expf(-x1))) * x3;
      g_pool[(size_t)prow*2816 + col] = f2bf(g);
    }
  }
}

// down: A = g_pool rows (contiguous), B = w2t, epilogue stores into per-slot buffers (no atomics)
__global__ __launch_bounds__(256) void moe_down128(const u16* __restrict__ g_pool, const u16* __restrict__ w2t,
        const int* __restrict__ meta, const float* __restrict__ pw,
        const int* __restrict__ poff, const int* __restrict__ pcnt,
        const int* __restrict__ tileinfo, const int* __restrict__ ntiles,
        float* __restrict__ out_slot){
  const int y = blockIdx.y;
  if (y >= *ntiles) return;
  const int ti = tileinfo[y];
  const int e = ti>>16, mt = ti & 0xffff;
  const int base = poff[e], cnt = pcnt[e];
  const int nbase = blockIdx.x*128;
  __shared__ u16 As[128*32];
  __shared__ u16 Bs[128*32];
  const int t = threadIdx.x;
  const int wave = t>>6, lane = t&63, lrow = lane&15, quad = lane>>4;
  const int wm = (wave&1)*64, wn = (wave>>1)*64;
  const int ca = wave*128 + lane;
  const int r0 = ca>>2;
  const int jsw = (ca&3) ^ ((r0 + (r0>>2))&3);
  const u16* a0 = g_pool + (size_t)(base + mt*128 + r0)*2816 + jsw*8;
  const u16* a1 = a0 + (size_t)16*2816;
  const u16* b0 = w2t + (size_t)e*1024*2816 + (size_t)(nbase + r0)*2816 + jsw*8;
  const u16* b1 = b0 + (size_t)16*2816;
  u16* lA = As + wave*1024;
  u16* lB = Bs + wave*1024;
  const int swz = (lrow + (lrow>>2)) & 3;
  floatx4 acc[4][4];
  #pragma unroll
  for (int i=0;i<4;++i)
  #pragma unroll
  for (int j=0;j<4;++j) acc[i][j] = floatx4{0.f,0.f,0.f,0.f};
  for (int k0=0;k0<2816;k0+=32){
    __syncthreads();
    gl16(a0, lA); gl16(a1, lA+512);
    gl16(b0, lB); gl16(b1, lB+512);
    a0 += 32; a1 += 32; b0 += 32; b1 += 32;
    __syncthreads();
    bf16x8 af[4], bfr[4];
    #pragma unroll
    for (int mi=0;mi<4;++mi) af[mi]  = *(const bf16x8*)&As[(((wm+mi*16+lrow)<<2) + (quad^swz))*8];
    #pragma unroll
    for (int ni=0;ni<4;++ni) bfr[ni] = *(const bf16x8*)&Bs[(((wn+ni*16+lrow)<<2) + (quad^swz))*8];
    #pragma unroll
    for (int mi=0;mi<4;++mi)
    #pragma unroll
    for (int ni=0;ni<4;++ni) acc[mi][ni] = mfma16(af[mi], bfr[ni], acc[mi][ni]);
  }
  #pragma unroll
  for (int mi=0;mi<4;++mi)
  #pragma unroll
  for (int ni=0;ni<4;++ni)
  #pragma unroll
  for (int i=0;i<4;++i){
    int ml = mt*128 + wm + mi*16 + quad*4 + i;
    if (ml < cnt){
      int mm = meta[base+ml];
      int token = mm>>1, slot = mm&1;
      float wgt = pw[base+ml];
      int col = nbase + wn + ni*16 + lrow;
      out_slot[(size_t)slot*4194304 + (size_t)token*1024 + col] = wgt*acc[mi][ni][i];
    }
  }
}

// ------------------------------ launcher ------------------------------
extern "C" void kernel_launch(void* const* d_in, const int* in_sizes, int n_in,
                              void* d_out, int out_size, void* d_ws, size_t ws_size,
                              hipStream_t stream){
  const float* x    = (const float*)d_in[0];
  const float* fcos = (const float*)d_in[3];
  const float* fsin = (const float*)d_in[4];
  const float* anw  = (const float*)d_in[5];
  const float* fnw  = (const float*)d_in[6];
  const float* wq   = (const float*)d_in[7];
  const float* wk   = (const float*)d_in[8];
  const float* wv_  = (const float*)d_in[9];
  const float* wo   = (const float*)d_in[10];
  const float* gw   = (const float*)d_in[11];
  const float* w1e  = (const float*)d_in[12];
  const float* w2e  = (const float*)d_in[13];
  const float* w3e  = (const float*)d_in[14];
  float* out = (float*)d_out;

  char* ws = (char*)d_ws;
  size_t off = 0;
  auto alloc = [&](size_t b)->void*{ void* p = ws + off; off += (b + 255) & ~(size_t)255; return p; };

  u16* wqkv_t = (u16*)alloc(3145728);     // [1536][1024] bf16 (wq^T | wk^T | wv^T)
  u16* wo_t   = (u16*)alloc(2097152);     // [1024][1024]
  u16* w1t    = (u16*)alloc(46137344);    // [8][2816][1024]
  u16* w3t    = (u16*)alloc(46137344);
  u16* w2t    = (u16*)alloc(46137344);    // [8][1024][2816]
  u16* xn_b   = (u16*)alloc(8388608);
  float* qkv_f= (float*)alloc(25165824);  // [4096][1536]  (reused as out_slot after attention)
  u16* q_b    = (u16*)alloc(8388608);     // (second half of out_slot reuse)
  u16* k_b    = (u16*)alloc(2097152);
  u16* v_b    = (u16*)alloc(2097152);
  u16* at_b   = (u16*)alloc(8388608);
  float* h_f  = (float*)alloc(16777216);
  u16* hn_b   = (u16*)alloc(8388608);
  int2* tidx  = (int2*)alloc(32768);
  float2* tw  = (float2*)alloc(32768);
  int* pcnt   = (int*)alloc(256);
  int* poff   = (int*)alloc(256);
  int* pcur   = (int*)alloc(256);
  int* tinfo  = (int*)alloc(512);
  int* ntl    = (int*)alloc(256);
  int* meta   = (int*)alloc(37376);       // 9344 slots
  float* pw   = (float*)alloc(37376);
  u16* g_pool = (u16*)alloc(52625408);    // 9344 x 2816 bf16

  float* out_slot = (float*)qkv_f;        // 32 MB: qkv_f (24 MB) + q_b (8 MB), both dead post-attention

  // transpose-cast weights (fp32 [K][N] -> bf16 [N][K])
  tcast_k<<<dim3(16,16,1), 256, 0, stream>>>(wq,  wqkv_t,            1024, 1024);
  tcast_k<<<dim3(4,16,1),  256, 0, stream>>>(wk,  wqkv_t + 1048576,  1024, 256);
  tcast_k<<<dim3(4,16,1),  256, 0, stream>>>(wv_, wqkv_t + 1310720,  1024, 256);
  tcast_k<<<dim3(16,16,1), 256, 0, stream>>>(wo,  wo_t,              1024, 1024);
  tcast_k<<<dim3(44,16,8), 256, 0, stream>>>(w1e, w1t,               1024, 2816);
  tcast_k<<<dim3(44,16,8), 256, 0, stream>>>(w3e, w3t,               1024, 2816);
  tcast_k<<<dim3(16,44,8), 256, 0, stream>>>(w2e, w2t,               2816, 1024);

  // attention input norm
  rmsnorm_k<<<4096, 256, 0, stream>>>(x, anw, xn_b);

  // fused QKV projection: [4096,1024] x [1536,1024]^T -> fp32 [4096][1536]
  gemm128<0><<<dim3(12,32), 256, 0, stream>>>(xn_b, wqkv_t, 4096, 1536, 1024, qkv_f, nullptr);

  // RoPE q,k + cast v
  rope_k<<<8192, 256, 0, stream>>>(qkv_f, q_b, fcos, fsin, 16, 2097152, 1536, 0);
  rope_k<<<2048, 256, 0, stream>>>(qkv_f, k_b, fcos, fsin, 4,  524288, 1536, 1024);
  vcast_k<<<512, 256, 0, stream>>>(qkv_f, v_b);

  // flash attention (paired q-tiles, uniform load)
  attn2_k<<<dim3(8,16,4), 256, 0, stream>>>(q_b, k_b, v_b, at_b);

  // output projection + residual -> h
  gemm128<1><<<dim3(8,32), 256, 0, stream>>>(at_b, wo_t, 4096, 1024, 1024, h_f, x);

  // ffn norm (bf16 for experts)
  rmsnorm_k<<<4096, 256, 0, stream>>>(h_f, fnw, hn_b);

  // routing
  init_k<<<1, 64, 0, stream>>>(pcnt);
  gate_top2<<<1024, 256, 0, stream>>>(h_f, fnw, gw, tidx, tw, pcnt);
  offsets_k<<<1, 64, 0, stream>>>(pcnt, poff, pcur, tinfo, ntl);
  scatter_k<<<16, 256, 0, stream>>>(tidx, tw, pcur, meta, pw);

  // expert GEMMs
  moe_up128<<<dim3(44,72), 256, 0, stream>>>(hn_b, w1t, w3t, meta, poff, pcnt, tinfo, ntl, g_pool);
  moe_down128<<<dim3(8,72), 256, 0, stream>>>(g_pool, w2t, meta, pw, poff, pcnt, tinfo, ntl, out_slot);

  // final residual add: out = h + slot0 + slot1
  final_add<<<4096, 256, 0, stream>>>(h_f, out_slot, out_slot + 4194304, out, 1048576);
}